// Round 9
// baseline (154.880 us; speedup 1.0000x reference)
//
#include <hip/hip_runtime.h>
#include <math.h>

#define B 2
#define C 64
#define N 4096
#define HID 128
#define NH 4
#define DH 32
#define PP 32              /* positions per block */
#define CPB (N / PP)       /* 128 chunks per batch */

#define SCALE 0.17677669529663687f /* 32^-0.5 */

// ---------------- K_A: norm + KV projection + partial M = K V^T ----------------
// grid: B*CPB = 256 blocks of 256. Each block: 32 positions, full pipeline to
// partial M (4 heads x 32x32) for its chunk.
__global__ __launch_bounds__(256) void ka_kv_m(
    const float* __restrict__ x, const float* __restrict__ g,
    const float* __restrict__ wqkv, float* __restrict__ mpart)
{
    __shared__ float xs[C][36];
    __shared__ float kvs[256][36];
    __shared__ float part[8][PP];
    __shared__ float scale_s[PP];
    __shared__ float gs[C];

    const int t = threadIdx.x;
    const int bx = blockIdx.x;
    const int b = bx >> 7;
    const int p0 = (bx & 127) * PP;

    /* stage x tile [64c][32p] : 512 float4 */
    const float* xb = x + (size_t)b * C * N + p0;
    #pragma unroll
    for (int it = 0; it < 2; ++it) {
        int idx = t + it * 256;
        int row = idx >> 3, p4 = (idx & 7) * 4;
        *(float4*)&xs[row][p4] = *(const float4*)(xb + (size_t)row * N + p4);
    }
    if (t < C) gs[t] = g[t];
    __syncthreads();

    { /* norm partials: 8 groups x 8 channels */
        int p = t & 31, cg = t >> 5;
        float s = 0.f;
        #pragma unroll
        for (int c = 0; c < 8; ++c) { float v = xs[cg * 8 + c][p]; s += v * v; }
        part[cg][p] = s;
    }
    __syncthreads();
    if (t < PP) {
        float ss = 0.f;
        #pragma unroll
        for (int i = 0; i < 8; ++i) ss += part[i][t];
        scale_s[t] = 8.0f / fmaxf(sqrtf(ss), 1e-12f); /* sqrt(C)=8, torch eps */
    }
    __syncthreads();
    #pragma unroll
    for (int it = 0; it < 8; ++it) {
        int idx = t + it * 256;
        int c = idx >> 5, p = idx & 31;
        xs[c][p] *= scale_s[p] * gs[c];
    }
    __syncthreads();

    /* KV projection: kvs row r (r<128 = k, r>=128 = v) = wqkv row 128+r */
    {
        const int p = t & 31, tg = t >> 5;
        for (int rr = 0; rr < 32; ++rr) {
            int r = tg * 32 + rr;
            const float4* wr = (const float4*)(wqkv + (size_t)(HID + r) * C);
            float acc = 0.f;
            #pragma unroll
            for (int c4 = 0; c4 < 16; ++c4) {
                float4 w4 = wr[c4];
                acc += w4.x * xs[c4 * 4 + 0][p] + w4.y * xs[c4 * 4 + 1][p]
                     + w4.z * xs[c4 * 4 + 2][p] + w4.w * xs[c4 * 4 + 3][p];
            }
            kvs[r][p] = acc;
        }
    }
    __syncthreads();

    /* partial M: thread t -> e = t>>3, dbase = t&7; entries (h, e, dbase+8k).
       v-row = 128 + h*32 + (t&7) + 8k: 8 lanes/group hit 8 distinct rows,
       row stride 36 floats -> banks 0,4,..,28 -> conflict-free b128 reads. */
    {
        const int e = t >> 3, db = t & 7;
        float acc[4][4];
        #pragma unroll
        for (int h = 0; h < 4; ++h)
            #pragma unroll
            for (int k = 0; k < 4; ++k) acc[h][k] = 0.f;
        #pragma unroll
        for (int h = 0; h < 4; ++h) {
            #pragma unroll
            for (int j4 = 0; j4 < 8; ++j4) {
                const float4 k4 = *(const float4*)&kvs[h * DH + e][j4 * 4];
                #pragma unroll
                for (int k = 0; k < 4; ++k) {
                    const float4 v4 =
                        *(const float4*)&kvs[128 + h * DH + db + 8 * k][j4 * 4];
                    acc[h][k] += k4.x * v4.x + k4.y * v4.y
                               + k4.z * v4.z + k4.w * v4.w;
                }
            }
        }
        float* mp = mpart + (size_t)bx * 4096;
        #pragma unroll
        for (int h = 0; h < 4; ++h)
            #pragma unroll
            for (int k = 0; k < 4; ++k)
                mp[h * 1024 + e * 32 + db + 8 * k] = acc[h][k];
    }
}

// ---------------- K_B: reduce M partials + fold w_out -> U ----------------
// grid: B*NH = 8 blocks of 256. U[b][o][h*32+e] = sum_d wout[o][h*32+d]*M[e][d]
__global__ __launch_bounds__(256) void kb_fold_u(
    const float* __restrict__ mpart, const float* __restrict__ wout,
    float* __restrict__ U)
{
    __shared__ float Ms[DH][36];
    const int t = threadIdx.x;
    const int bx = blockIdx.x;
    const int b = bx >> 2, h = bx & 3;

    float4 s4 = make_float4(0.f, 0.f, 0.f, 0.f);
    const float* mp = mpart + (size_t)h * 1024 + 4 * t;
    for (int ch = 0; ch < CPB; ++ch) {
        const float4 m4 = *(const float4*)(mp + (size_t)(b * CPB + ch) * 4096);
        s4.x += m4.x; s4.y += m4.y; s4.z += m4.z; s4.w += m4.w;
    }
    *(float4*)&Ms[t >> 3][(t & 7) * 4] = s4;
    __syncthreads();

    #pragma unroll
    for (int it = 0; it < 8; ++it) {
        int u = t + it * 256;                /* o = u&63, e = u>>6 in [0,32) */
        int o = u & 63, e = u >> 6;
        float s = 0.f;
        #pragma unroll
        for (int d4 = 0; d4 < 8; ++d4) {
            const float4 w4 = *(const float4*)(wout + (size_t)o * HID + h * DH + d4 * 4);
            s += w4.x * Ms[e][d4 * 4 + 0] + w4.y * Ms[e][d4 * 4 + 1]
               + w4.z * Ms[e][d4 * 4 + 2] + w4.w * Ms[e][d4 * 4 + 3];
        }
        U[((size_t)b * C + o) * HID + h * DH + e] = s;
    }
}

// ---------------- K_C: norm + Q projection + out = U q + b_out + x ----------------
// grid: B*CPB = 256 blocks of 256.
__global__ __launch_bounds__(256) void kc_q_final(
    const float* __restrict__ x, const float* __restrict__ g,
    const float* __restrict__ wqkv, const float* __restrict__ U,
    const float* __restrict__ bout, float* __restrict__ out)
{
    __shared__ float xs[C][36];
    __shared__ float qls[HID][36];
    __shared__ float part[8][PP];
    __shared__ float scale_s[PP];
    __shared__ float gs[C];

    const int t = threadIdx.x;
    const int bx = blockIdx.x;
    const int b = bx >> 7;
    const int p0 = (bx & 127) * PP;

    const float* xb = x + (size_t)b * C * N + p0;
    #pragma unroll
    for (int it = 0; it < 2; ++it) {
        int idx = t + it * 256;
        int row = idx >> 3, p4 = (idx & 7) * 4;
        *(float4*)&xs[row][p4] = *(const float4*)(xb + (size_t)row * N + p4);
    }
    if (t < C) gs[t] = g[t];
    __syncthreads();

    {
        int p = t & 31, cg = t >> 5;
        float s = 0.f;
        #pragma unroll
        for (int c = 0; c < 8; ++c) { float v = xs[cg * 8 + c][p]; s += v * v; }
        part[cg][p] = s;
    }
    __syncthreads();
    if (t < PP) {
        float ss = 0.f;
        #pragma unroll
        for (int i = 0; i < 8; ++i) ss += part[i][t];
        scale_s[t] = 8.0f / fmaxf(sqrtf(ss), 1e-12f);
    }
    __syncthreads();
    #pragma unroll
    for (int it = 0; it < 8; ++it) {
        int idx = t + it * 256;
        int c = idx >> 5, p = idx & 31;
        xs[c][p] *= scale_s[p] * gs[c];
    }
    __syncthreads();

    /* Q projection (wqkv rows 0..127), pre-scaled by 1/sqrt(32) */
    {
        const int p = t & 31, tg = t >> 5;
        for (int rr = 0; rr < 16; ++rr) {
            int r = tg * 16 + rr;
            const float4* wr = (const float4*)(wqkv + (size_t)r * C);
            float acc = 0.f;
            #pragma unroll
            for (int c4 = 0; c4 < 16; ++c4) {
                float4 w4 = wr[c4];
                acc += w4.x * xs[c4 * 4 + 0][p] + w4.y * xs[c4 * 4 + 1][p]
                     + w4.z * xs[c4 * 4 + 2][p] + w4.w * xs[c4 * 4 + 3][p];
            }
            qls[r][p] = acc * SCALE;
        }
    }
    __syncthreads();

    /* out[o][p] = bout[o] + U[o][:]·q[:][p] + x[o][p] */
    {
        const int p = t & 31, tg = t >> 5;
        for (int oo = 0; oo < 8; ++oo) {
            int o = tg * 8 + oo;
            const float4* ur = (const float4*)(U + ((size_t)b * C + o) * HID);
            float acc = bout[o];
            #pragma unroll
            for (int c4 = 0; c4 < 32; ++c4) {
                float4 u4 = ur[c4];
                acc += u4.x * qls[c4 * 4 + 0][p] + u4.y * qls[c4 * 4 + 1][p]
                     + u4.z * qls[c4 * 4 + 2][p] + u4.w * qls[c4 * 4 + 3][p];
            }
            const size_t gi = ((size_t)b * C + o) * N + p0 + p;
            out[gi] = acc + x[gi];
        }
    }
}

extern "C" void kernel_launch(void* const* d_in, const int* in_sizes, int n_in,
                              void* d_out, int out_size, void* d_ws, size_t ws_size,
                              hipStream_t stream)
{
    const float* x    = (const float*)d_in[0];
    const float* g    = (const float*)d_in[1];
    const float* wqkv = (const float*)d_in[2];
    const float* wout = (const float*)d_in[3];
    const float* bout = (const float*)d_in[4];
    float* out = (float*)d_out;

    float* mpart = (float*)d_ws;                 /* 256*4096*4 = 4 MB */
    float* U     = mpart + (size_t)B * CPB * 4096; /* 64 KB */

    ka_kv_m   <<<B * CPB, 256, 0, stream>>>(x, g, wqkv, mpart);
    kb_fold_u <<<B * NH, 256, 0, stream>>>(mpart, wout, U);
    kc_q_final<<<B * CPB, 256, 0, stream>>>(x, g, wqkv, U, bout, out);
}

// Round 16
// 106.539 us; speedup vs baseline: 1.4537x; 1.4537x over previous
//
#include <hip/hip_runtime.h>
#include <math.h>

#define Nn 4096
#define SCALEq 0.17677669529663687f /* 32^-0.5 */

// ---------- KA: RMS norm + Gram partials (512 blocks x 256, 16 pos each) ----------
__global__ __launch_bounds__(256) void ka_gram(
    const float* __restrict__ x, const float* __restrict__ g,
    float* __restrict__ gpart, float* __restrict__ sarr)
{
    __shared__ float buf[1360]; /* xt[64][17]=1088 | part 256 @1088 | scale 16 @1344 */
    const int t = threadIdx.x, bx = blockIdx.x;
    const int b = bx >> 8, ch = bx & 255;
    const int p0 = ch * 16;
    const int row = t >> 2, p4 = (t & 3) * 4;
    const float* xb = x + (size_t)b * 64 * Nn + p0;
    float4 v4 = *(const float4*)(xb + (size_t)row * Nn + p4);
    buf[row * 17 + p4 + 0] = v4.x;
    buf[row * 17 + p4 + 1] = v4.y;
    buf[row * 17 + p4 + 2] = v4.z;
    buf[row * 17 + p4 + 3] = v4.w;
    __syncthreads();
    {
        const int p = t & 15, cgp = t >> 4; /* 16 groups x 4 channels */
        float s = 0.f;
        #pragma unroll
        for (int c = 0; c < 4; ++c) {
            float v = buf[(cgp * 4 + c) * 17 + p];
            s += v * v;
        }
        buf[1088 + cgp * 16 + p] = s;
    }
    __syncthreads();
    if (t < 16) {
        float ss = 0.f;
        #pragma unroll
        for (int i = 0; i < 16; ++i) ss += buf[1088 + i * 16 + t];
        float sv = 8.0f / fmaxf(sqrtf(ss), 1e-12f); /* sqrt(C)=8, torch eps */
        buf[1344 + t] = sv;
        sarr[(size_t)b * Nn + p0 + t] = sv;
    }
    __syncthreads();
    {
        const float gv = g[row];
        #pragma unroll
        for (int i = 0; i < 4; ++i)
            buf[row * 17 + p4 + i] *= gv * buf[1344 + p4 + i];
    }
    __syncthreads();
    { /* G partial: r = t>>2 (row), cq = t&3 (16-col slice), 16 indep acc */
        const int r = t >> 2, cq = t & 3;
        float acc[16];
        #pragma unroll
        for (int j = 0; j < 16; ++j) acc[j] = 0.f;
        #pragma unroll
        for (int p = 0; p < 16; ++p) {
            const float a = buf[r * 17 + p];
            #pragma unroll
            for (int j = 0; j < 16; ++j)
                acc[j] += a * buf[(cq * 16 + j) * 17 + p];
        }
        float* gp = gpart + (size_t)bx * 4096 + r * 64 + cq * 16;
        #pragma unroll
        for (int j4 = 0; j4 < 4; ++j4)
            *(float4*)(gp + j4 * 4) = make_float4(
                acc[j4*4], acc[j4*4+1], acc[j4*4+2], acc[j4*4+3]);
    }
}

// ---------- KB: reduce 256 Gram partials -> Gm (128 blocks x 256) ----------
__global__ __launch_bounds__(256) void kb_reduce(
    const float* __restrict__ gpart, float* __restrict__ Gm)
{
    __shared__ float4 pb[256];
    const int t = threadIdx.x, bx = blockIdx.x;
    const int b = bx >> 6, seg = bx & 63;      /* G row seg */
    const int c4i = t & 15, rg = t >> 4;
    const float* base = gpart + (size_t)b * 256 * 4096 + seg * 64 + c4i * 4;
    float ax = 0, ay = 0, az = 0, aw = 0;
    #pragma unroll
    for (int rr = 0; rr < 16; ++rr) {
        const float4 v = *(const float4*)(base + (size_t)(rg * 16 + rr) * 4096);
        ax += v.x; ay += v.y; az += v.z; aw += v.w;
    }
    pb[rg * 16 + c4i] = make_float4(ax, ay, az, aw);
    __syncthreads();
    if (t < 16) {
        float sx = 0, sy = 0, sz = 0, sw = 0;
        #pragma unroll
        for (int i = 0; i < 16; ++i) {
            const float4 v = pb[i * 16 + t];
            sx += v.x; sy += v.y; sz += v.z; sw += v.w;
        }
        *(float4*)(Gm + (size_t)b * 4096 + seg * 64 + t * 4) =
            make_float4(sx, sy, sz, sw);
    }
}

// ---------- KC: G -> T=W_k G -> M_h=T_h W_vh^T -> U -> W_f (8 blocks x 256) ----------
__global__ __launch_bounds__(256) void kc_chain(
    const float* __restrict__ Gm, const float* __restrict__ wqkv,
    const float* __restrict__ wout, float* __restrict__ Wf)
{
    __shared__ float buf[13056];
    const int t = threadIdx.x, bx = blockIdx.x;
    const int b = bx >> 2, q = bx & 3;      /* q: 16-output slice */
    float* Gs = buf;        /* [64][68]  */
    float* Ts = buf + 4352; /* [128][68] */
    float* Ms = buf;        /* [128][33] (Gs dead) */
    float* Us = buf + 4352; /* [16][132] (Ts dead) */
    #pragma unroll
    for (int i = 0; i < 4; ++i) {
        int s = t + i * 256;
        float4 v = *(const float4*)(Gm + (size_t)b * 4096 + 4 * s);
        *(float4*)&Gs[(s >> 4) * 68 + (s & 15) * 4] = v;
    }
    __syncthreads();
    { /* T rows: rT = t>>1, 32 cols each */
        const int rT = t >> 1, cc0 = (t & 1) * 32;
        float acc[32];
        #pragma unroll
        for (int j = 0; j < 32; ++j) acc[j] = 0.f;
        for (int c = 0; c < 64; ++c) {
            const float wk = wqkv[(size_t)(128 + rT) * 64 + c];
            #pragma unroll
            for (int j4 = 0; j4 < 8; ++j4) {
                const float4 g4 = *(const float4*)&Gs[c * 68 + cc0 + j4 * 4];
                acc[j4*4+0] += wk * g4.x; acc[j4*4+1] += wk * g4.y;
                acc[j4*4+2] += wk * g4.z; acc[j4*4+3] += wk * g4.w;
            }
        }
        #pragma unroll
        for (int j4 = 0; j4 < 8; ++j4)
            *(float4*)&Ts[rT * 68 + cc0 + j4 * 4] = make_float4(
                acc[j4*4], acc[j4*4+1], acc[j4*4+2], acc[j4*4+3]);
    }
    __syncthreads();
    { /* M rows: rM = t>>1, 16 d each; h = rM>>5 */
        const int rM = t >> 1, d0 = (t & 1) * 16;
        const int h = rM >> 5;
        float acc[16];
        #pragma unroll
        for (int d = 0; d < 16; ++d) acc[d] = 0.f;
        #pragma unroll
        for (int c4 = 0; c4 < 16; ++c4) {
            const float4 ts4 = *(const float4*)&Ts[rM * 68 + c4 * 4];
            #pragma unroll
            for (int d = 0; d < 16; ++d) {
                const float4 wv4 = *(const float4*)
                    &wqkv[(size_t)(256 + h * 32 + d0 + d) * 64 + c4 * 4];
                acc[d] += ts4.x*wv4.x + ts4.y*wv4.y + ts4.z*wv4.z + ts4.w*wv4.w;
            }
        }
        #pragma unroll
        for (int d = 0; d < 16; ++d) Ms[rM * 33 + d0 + d] = acc[d];
    }
    __syncthreads();
    { /* U[o][r], o in q-slice: oo = t>>4, r0 = (t&15)*8 */
        const int oo = t >> 4, r0 = (t & 15) * 8;
        const int o = q * 16 + oo;
        const int h = r0 >> 5;
        #pragma unroll
        for (int rr = 0; rr < 8; ++rr) {
            const int r = r0 + rr;
            float s = 0.f;
            #pragma unroll
            for (int d4 = 0; d4 < 8; ++d4) {
                const float4 wo4 = *(const float4*)
                    &wout[(size_t)o * 128 + h * 32 + d4 * 4];
                s += wo4.x * Ms[r*33 + d4*4+0] + wo4.y * Ms[r*33 + d4*4+1]
                   + wo4.z * Ms[r*33 + d4*4+2] + wo4.w * Ms[r*33 + d4*4+3];
            }
            Us[oo * 132 + r] = s;
        }
    }
    __syncthreads();
    { /* W_f[o][c] = SCALE * sum_r U[o][r] W_q[r][c] */
        const int oo = t >> 4, c0 = (t & 15) * 4;
        float a0 = 0, a1 = 0, a2 = 0, a3 = 0;
        for (int r = 0; r < 128; ++r) {
            const float u = Us[oo * 132 + r];
            const float4 wq4 = *(const float4*)&wqkv[(size_t)r * 64 + c0];
            a0 += u * wq4.x; a1 += u * wq4.y; a2 += u * wq4.z; a3 += u * wq4.w;
        }
        *(float4*)(Wf + (size_t)b * 4096 + (q * 16 + oo) * 64 + c0) =
            make_float4(a0*SCALEq, a1*SCALEq, a2*SCALEq, a3*SCALEq);
    }
}

// ---------- KD: out = W_f x_hat + b_out + x (512 blocks x 256, 16 pos each) ----------
__global__ __launch_bounds__(256) void kd_out(
    const float* __restrict__ x, const float* __restrict__ g,
    const float* __restrict__ sarr, const float* __restrict__ Wf,
    const float* __restrict__ bout, float* __restrict__ out)
{
    __shared__ float buf[5440]; /* xt[64][17]=1088 | Wfs[64][68]=4352 @1088 */
    const int t = threadIdx.x, bx = blockIdx.x;
    const int b = bx >> 8, ch = bx & 255;
    const int p0 = ch * 16;
    const int row = t >> 2, p4 = (t & 3) * 4;
    const float* xb = x + (size_t)b * 64 * Nn + p0;
    float4 v4 = *(const float4*)(xb + (size_t)row * Nn + p4);
    float4 s4 = *(const float4*)(sarr + (size_t)b * Nn + p0 + p4);
    const float gv = g[row];
    buf[row*17 + p4+0] = v4.x * gv * s4.x;
    buf[row*17 + p4+1] = v4.y * gv * s4.y;
    buf[row*17 + p4+2] = v4.z * gv * s4.z;
    buf[row*17 + p4+3] = v4.w * gv * s4.w;
    float* Wfs = buf + 1088;
    #pragma unroll
    for (int i = 0; i < 4; ++i) {
        int s = t + i * 256;
        float4 w = *(const float4*)(Wf + (size_t)b * 4096 + 4 * s);
        *(float4*)&Wfs[(s >> 4) * 68 + (s & 15) * 4] = w;
    }
    __syncthreads();

    const int p = t & 15, og = t >> 4;
    const int o0 = og * 4;
    float acc[4];
    #pragma unroll
    for (int oo = 0; oo < 4; ++oo) acc[oo] = bout[o0 + oo];
    #pragma unroll
    for (int c4 = 0; c4 < 16; ++c4) {
        const float x0 = buf[(c4*4+0)*17 + p];
        const float x1 = buf[(c4*4+1)*17 + p];
        const float x2 = buf[(c4*4+2)*17 + p];
        const float x3 = buf[(c4*4+3)*17 + p];
        #pragma unroll
        for (int oo = 0; oo < 4; ++oo) {
            const float4 w4 = *(const float4*)&Wfs[(o0+oo)*68 + c4*4];
            acc[oo] += w4.x*x0 + w4.y*x1 + w4.z*x2 + w4.w*x3;
        }
    }
    #pragma unroll
    for (int oo = 0; oo < 4; ++oo) {
        const size_t gi = ((size_t)b * 64 + o0 + oo) * Nn + p0 + p;
        out[gi] = acc[oo] + x[gi];
    }
}

extern "C" void kernel_launch(void* const* d_in, const int* in_sizes, int n_in,
                              void* d_out, int out_size, void* d_ws, size_t ws_size,
                              hipStream_t stream)
{
    const float* x    = (const float*)d_in[0];
    const float* g    = (const float*)d_in[1];
    const float* wqkv = (const float*)d_in[2];
    const float* wout = (const float*)d_in[3];
    const float* bout = (const float*)d_in[4];
    float* out = (float*)d_out;

    float* gpart = (float*)d_ws;                 /* 512*4096 floats = 8 MB */
    float* Gm    = gpart + (size_t)512 * 4096;   /* 2*4096 */
    float* sarr  = Gm + 2 * 4096;                /* 2*4096 */
    float* Wf    = sarr + 2 * 4096;              /* 2*4096 */

    ka_gram  <<<512, 256, 0, stream>>>(x, g, gpart, sarr);
    kb_reduce<<<128, 256, 0, stream>>>(gpart, Gm);
    kc_chain <<<8,   256, 0, stream>>>(Gm, wqkv, wout, Wf);
    kd_out   <<<512, 256, 0, stream>>>(x, g, sarr, Wf, bout, out);
}